// Round 4
// baseline (498.660 us; speedup 1.0000x reference)
//
#include <hip/hip_runtime.h>

#define N_NODES 50000
#define N_EDGES 600000
#define N_RELS  19
#define D_IN    128
#define D_HID   64
#define D_OUT   2
#define NBD     ((N_NODES + 63) >> 6)            // 782 dst-buckets (64 nodes each)
#define NSEG    (NBD * N_RELS)                   // 14858 (bucket, rel) segments
#define PREP_ELEMS (N_RELS * D_HID * D_IN + 64 * 64 + D_HID * D_IN)  // 167936
#define PREP_BLOCKS ((PREP_ELEMS + 255) / 256)   // 656

typedef unsigned short u16;
typedef unsigned int   u32;
typedef __attribute__((ext_vector_type(8))) short sfrag;   // 8 bf16 (4 VGPRs)
typedef __attribute__((ext_vector_type(4))) float f32x4;   // 4 fp32 acc

__device__ __forceinline__ u16 f2bf(float f){
  union { float f; u32 i; } v; v.f = f;
  u32 r = v.i + 0x7fffu + ((v.i >> 16) & 1u);  // RNE
  return (u16)(r >> 16);
}
__device__ __forceinline__ u32 pack2(float lo, float hi){
  return (u32)f2bf(lo) | ((u32)f2bf(hi) << 16);
}

// feat->featb bf16 (float4), (dst-bucket, rel) segment histogram.
__global__ __launch_bounds__(256) void k_pre(const float* __restrict__ feat,
                                             u16* __restrict__ featb,
                                             const int* __restrict__ dst,
                                             const int* __restrict__ et,
                                             int* __restrict__ seg_hist){
  int i = blockIdx.x * 256 + threadIdx.x;          // 1.6M float4 elems
  float4 f = ((const float4*)feat)[i];
  uint2 p; p.x = pack2(f.x, f.y); p.y = pack2(f.z, f.w);
  ((uint2*)featb)[i] = p;
  if (i < N_EDGES) {
    int key = (dst[i] >> 6) * N_RELS + et[i];
    atomicAdd(&seg_hist[key * 4], 1);              // 16B-padded counters
  }
}

// Block 0: segment scan (seg_off/cur_seg). Blocks 1..: weight transform:
// W1Tb [19][64][128] (j-major); W2allT [64][64]: row j=2r+o -> W2[r][:,o],
// rows 38/39 -> loop2 cols (layer-2 self-loop as extra GEMM cols), rest zero;
// loop1Tb [64][128].
__global__ __launch_bounds__(256) void k_prep(
    const int* __restrict__ seg_hist, int* __restrict__ seg_off,
    int* __restrict__ cur_seg,
    const float* __restrict__ W1, const float* __restrict__ loop1,
    const float* __restrict__ W2, const float* __restrict__ loop2,
    u16* __restrict__ W1Tb, u16* __restrict__ loop1Tb,
    u16* __restrict__ W2allT){
  if (blockIdx.x == 0) {                        // ---- segment scan ----
    __shared__ int ps[256];
    int tid = threadIdx.x;
    const int PER = (NSEG + 255) / 256;         // 59
    int lo = tid * PER, hi = lo + PER; if (hi > NSEG) hi = NSEG; if (lo > NSEG) lo = NSEG;
    int s = 0;
    for (int i = lo; i < hi; ++i) s += seg_hist[i * 4];
    ps[tid] = s;
    __syncthreads();
    if (tid == 0) { int a = 0; for (int j = 0; j < 256; ++j) { int x = ps[j]; ps[j] = a; a += x; } }
    __syncthreads();
    int eo = ps[tid];
    for (int i = lo; i < hi; ++i) {
      int c = seg_hist[i * 4];
      seg_off[i] = eo; cur_seg[i * 4] = eo;
      eo += c;
    }
    if (hi == NSEG) seg_off[NSEG] = eo;         // == N_EDGES
    return;
  }
  int idx = (blockIdx.x - 1) * 256 + threadIdx.x;
  const int T1  = N_RELS * D_HID * D_IN;        // 155648
  const int T2c = T1 + 64 * 64;                 // 159744
  const int T3  = T2c + D_HID * D_IN;           // 167936
  if (idx < T1) {
    int r = idx / (D_HID * D_IN);
    int t = idx - r * (D_HID * D_IN);
    int j = t >> 7, d = t & 127;
    W1Tb[idx] = f2bf(W1[(r * D_IN + d) * D_HID + j]);
  } else if (idx < T2c) {
    int k2 = idx - T1;
    int j = k2 >> 6, k = k2 & 63;
    float val = 0.f;
    if (j < N_RELS * D_OUT)      val = W2[((j >> 1) * D_HID + k) * D_OUT + (j & 1)];
    else if (j == 38)            val = loop2[k * 2];
    else if (j == 39)            val = loop2[k * 2 + 1];
    W2allT[k2] = f2bf(val);
  } else if (idx < T3) {
    int k2 = idx - T2c;
    int j = k2 >> 7, d = k2 & 127;
    loop1Tb[k2] = f2bf(loop1[d * D_HID + j]);
  }
}

// Scatter edges into perm, grouped by (dst-bucket, rel).
__global__ __launch_bounds__(256) void k_scatter(const int* __restrict__ dst,
                                                 const int* __restrict__ et,
                                                 int* __restrict__ cur_seg,
                                                 int* __restrict__ perm){
  int e = blockIdx.x * 256 + threadIdx.x;
  if (e >= N_EDGES) return;
  int key = (dst[e] >> 6) * N_RELS + et[e];
  int p = atomicAdd(&cur_seg[key * 4], 1);
  perm[p] = e;
}

// Layer-1 edge GEMM + in-LDS aggregation. One block per dst-bucket (64 nodes).
// Waves independently grab rel-pure 64-edge wave-tiles (round-robin), gather
// featb rows (L3-resident), read B-fragments DIRECT from L2-resident W1Tb
// (no LDS staging, no per-tile barriers), MFMA, and LDS-atomicAdd f32 results
// into the bucket accumulator. One coalesced flush -> agg1f (msg sums, f32).
__global__ __launch_bounds__(256, 4) void k_edge1(
    const u16* __restrict__ featb, const u16* __restrict__ W1Tb,
    const int* __restrict__ src, const int* __restrict__ dst,
    const int* __restrict__ perm, const int* __restrict__ seg_off,
    float* __restrict__ agg1f){
  __shared__ float agg[64][68];                 // 17408 B, padded stride
  __shared__ int wdl[256];                      // per-wave 64 dst-local ids
  int tid = threadIdx.x, lane = tid & 63, w = tid >> 6;
  int r16 = lane & 15, c4 = lane >> 4;
  int kb = blockIdx.x;
  for (int i = tid; i < 64 * 68; i += 256) (&agg[0][0])[i] = 0.f;
  __syncthreads();

  int tcnt = 0;
  int sb = kb * N_RELS;
  int sPrev = seg_off[sb];
  for (int rel = 0; rel < N_RELS; ++rel) {
    int s0 = sPrev, s1 = seg_off[sb + rel + 1];
    sPrev = s1;
    int c = s1 - s0;
    int nt = (c + 63) >> 6;
    const u16* bp = W1Tb + (size_t)rel * (D_HID * D_IN);
    for (int t = 0; t < nt; ++t, ++tcnt) {
      if ((tcnt & 3) != w) continue;            // wave round-robin, no sync
      int ts = s0 + (t << 6);
      int vc = c - (t << 6); if (vc > 64) vc = 64;
      sfrag aF[4][4];
      #pragma unroll
      for (int mt = 0; mt < 4; ++mt) {
        int row = mt * 16 + r16;
        int rr = row < vc ? row : vc - 1;
        int e = perm[ts + rr];
        if (c4 == 0) wdl[w * 64 + row] = (row < vc) ? (dst[e] & 63) : -1;
        const u16* ap = featb + (size_t)src[e] * D_IN + c4 * 8;
        #pragma unroll
        for (int kk = 0; kk < 4; ++kk)
          aF[mt][kk] = *(const sfrag*)(ap + kk * 32);
      }
      #pragma unroll
      for (int ct = 0; ct < 4; ++ct) {
        int col = ct * 16 + r16;
        sfrag bF[4];
        #pragma unroll
        for (int kk = 0; kk < 4; ++kk)
          bF[kk] = *(const sfrag*)(bp + (size_t)col * D_IN + kk * 32 + c4 * 8);
        #pragma unroll
        for (int mt = 0; mt < 4; ++mt) {
          f32x4 acc = {0.f, 0.f, 0.f, 0.f};
          #pragma unroll
          for (int kk = 0; kk < 4; ++kk)
            acc = __builtin_amdgcn_mfma_f32_16x16x32_bf16(aF[mt][kk], bF[kk], acc, 0, 0, 0);
          int4 dlq = *((const int4*)&wdl[w * 64 + mt * 16 + c4 * 4]);
          int dls[4] = {dlq.x, dlq.y, dlq.z, dlq.w};
          #pragma unroll
          for (int reg = 0; reg < 4; ++reg)
            if (dls[reg] >= 0) atomicAdd(&agg[dls[reg]][col], acc[reg]);
        }
      }
    }
  }
  __syncthreads();
  { int row = tid >> 2, q = tid & 3;            // coalesced 64B/thread flush
    int n = kb * 64 + row;
    if (n < N_NODES) {
      float4* d = (float4*)(agg1f + (size_t)n * D_HID + q * 16);
      const float4* s4 = (const float4*)&agg[row][q * 16];
      d[0] = s4[0]; d[1] = s4[1]; d[2] = s4[2]; d[3] = s4[3];
    } }
}

// Fused post: self-loop MFMA (feat@loop1) + f32 msg sums + b1 + relu -> h1 (LDS),
// then T2 MFMA: T2[n][2r+o] = h1[n]@W2[r][:,o]; cols 38/39 carry the layer-2
// self-loop (loop2) -> out init. One block per 64 nodes.
__global__ __launch_bounds__(256) void k_post(
    const u16* __restrict__ featb, const u16* __restrict__ loop1Tb,
    const float* __restrict__ b1, const float* __restrict__ agg1f,
    const u16* __restrict__ W2allT, const float* __restrict__ b2,
    float* __restrict__ T2f, float* __restrict__ out){
  __shared__ __align__(16) u16 Bls[64][136];    // loop1 tile, reused for W2
  __shared__ __align__(16) u16 msg[64][72];     // h1 bf16 rows
  int tid = threadIdx.x, lane = tid & 63, w = tid >> 6;
  int r16 = lane & 15, c4 = lane >> 4;
  int base = blockIdx.x * 64;
  { int j = tid >> 2, sg = tid & 3;
    const uint4* g = (const uint4*)(loop1Tb + j * 128) + sg * 4;
    uint4* d = (uint4*)&Bls[j][sg * 32];
    d[0] = g[0]; d[1] = g[1]; d[2] = g[2]; d[3] = g[3]; }
  int arow = base + w * 16 + r16; if (arow >= N_NODES) arow = N_NODES - 1;
  sfrag aF[4];
  #pragma unroll
  for (int kk = 0; kk < 4; ++kk)
    aF[kk] = *(const sfrag*)(featb + (size_t)arow * D_IN + kk * 32 + c4 * 8);
  __syncthreads();
  #pragma unroll
  for (int ct = 0; ct < 4; ++ct) {
    f32x4 acc = {0.f, 0.f, 0.f, 0.f};
    #pragma unroll
    for (int kk = 0; kk < 4; ++kk) {
      sfrag bF = *(const sfrag*)&Bls[ct * 16 + r16][kk * 32 + c4 * 8];
      acc = __builtin_amdgcn_mfma_f32_16x16x32_bf16(aF[kk], bF, acc, 0, 0, 0);
    }
    int col = ct * 16 + r16;
    float bias = b1[col];
    #pragma unroll
    for (int reg = 0; reg < 4; ++reg) {
      int row = w * 16 + c4 * 4 + reg;
      int n = base + row;
      float m = (n < N_NODES) ? agg1f[(size_t)n * D_HID + col] : 0.f;
      float v = acc[reg] + m + bias;
      v = v > 0.f ? v : 0.f;
      float o = __shfl_xor(v, 1);
      if (!(lane & 1))
        *(u32*)&msg[row][col] = pack2(v, o);
    }
  }
  __syncthreads();
  { int rw = tid >> 2, q = tid & 3;             // stage W2allT into Bls[.][0..63]
    uint4* d = (uint4*)&Bls[rw][0];
    const uint4* g = (const uint4*)(W2allT + rw * 64);
    d[q * 2] = g[q * 2]; d[q * 2 + 1] = g[q * 2 + 1]; }
  __syncthreads();
  sfrag aM[2];
  #pragma unroll
  for (int kk = 0; kk < 2; ++kk)
    aM[kk] = *(const sfrag*)&msg[w * 16 + r16][kk * 32 + c4 * 8];
  #pragma unroll
  for (int ct = 0; ct < 3; ++ct) {              // cols 0..47 (40+ unused)
    int col = ct * 16 + r16;
    f32x4 acc = {0.f, 0.f, 0.f, 0.f};
    #pragma unroll
    for (int kk = 0; kk < 2; ++kk) {
      sfrag bF = *(const sfrag*)&Bls[col][kk * 32 + c4 * 8];
      acc = __builtin_amdgcn_mfma_f32_16x16x32_bf16(aM[kk], bF, acc, 0, 0, 0);
    }
    #pragma unroll
    for (int reg = 0; reg < 4; ++reg) {
      int n = base + w * 16 + c4 * 4 + reg;
      if (n < N_NODES) {
        if (col < 38)        T2f[(size_t)n * 40 + col] = acc[reg];
        else if (col < 40)   out[n * 2 + (col - 38)] = acc[reg] + b2[col - 38];
      }
    }
  }
}

// Layer-2 finish: one block per dst-bucket; sequential perm walk, 8B T2 gather
// per edge, LDS f32 reduce, single += flush. No global atomics, no srel.
__global__ __launch_bounds__(256) void k_fin(
    const float* __restrict__ T2f, const int* __restrict__ perm,
    const int* __restrict__ src, const int* __restrict__ dst,
    const int* __restrict__ et, const int* __restrict__ seg_off,
    float* __restrict__ out){
  __shared__ float a2[64][2];
  int tid = threadIdx.x;
  int kb = blockIdx.x;
  if (tid < 128) (&a2[0][0])[tid] = 0.f;
  __syncthreads();
  int e0 = seg_off[kb * N_RELS], e1 = seg_off[kb * N_RELS + N_RELS];
  for (int p = e0 + tid; p < e1; p += 256) {
    int e = perm[p];
    float2 v = *(const float2*)(T2f + (size_t)src[e] * 40 + et[e] * 2);
    int dl = dst[e] & 63;
    atomicAdd(&a2[dl][0], v.x);
    atomicAdd(&a2[dl][1], v.y);
  }
  __syncthreads();
  if (tid < 128) {
    int row = tid >> 1, q = tid & 1;
    int n = kb * 64 + row;
    if (n < N_NODES) out[n * 2 + q] += a2[row][q];
  }
}

extern "C" void kernel_launch(void* const* d_in, const int* in_sizes, int n_in,
                              void* d_out, int out_size, void* d_ws, size_t ws_size,
                              hipStream_t stream){
  const float* feat  = (const float*)d_in[0];
  const float* W1    = (const float*)d_in[1];
  const float* loop1 = (const float*)d_in[2];
  const float* b1    = (const float*)d_in[3];
  const float* W2    = (const float*)d_in[4];
  const float* loop2 = (const float*)d_in[5];
  const float* b2    = (const float*)d_in[6];
  const int* src     = (const int*)d_in[7];
  const int* dst     = (const int*)d_in[8];
  const int* et      = (const int*)d_in[9];
  float* out = (float*)d_out;

  // workspace layout (16B-aligned), ~36.9 MB total.
  char* w = (char*)d_ws;
  u16*   W1Tb     = (u16*)(w);                   //  311296
  u16*   W2allT   = (u16*)(w + 311296);          //    8192 (64x64 bf16)
  u16*   loop1Tb  = (u16*)(w + 319488);          //   16384
  int*   seg_hist = (int*)(w + 335872);          //  237728 (14858 x 16B) [memset]
  int*   seg_off  = (int*)(w + 573600);          //   59440
  int*   cur_seg  = (int*)(w + 633040);          //  237728 (16B-padded)
  int*   perm     = (int*)(w + 870768);          // 2400000
  u16*   featb    = (u16*)(w + 3270768);         // 12.8 MB
  float* agg1f    = (float*)(w + 16070768);      // 12.81 MB (50048 x 64 f32)
  float* T2f      = (float*)(w + 28883056);      //  8.0 MB (50000 x 40 f32)
                                                 // -> 36883056 total

  hipMemsetAsync(w + 335872, 0, 237728, stream);
  k_pre     <<<6250, 256, 0, stream>>>(feat, featb, dst, et, seg_hist);
  k_prep    <<<1 + PREP_BLOCKS, 256, 0, stream>>>(seg_hist, seg_off, cur_seg,
                                                  W1, loop1, W2, loop2,
                                                  W1Tb, loop1Tb, W2allT);
  k_scatter <<<2344, 256, 0, stream>>>(dst, et, cur_seg, perm);
  k_edge1   <<<NBD, 256, 0, stream>>>(featb, W1Tb, src, dst, perm, seg_off, agg1f);
  k_post    <<<NBD, 256, 0, stream>>>(featb, loop1Tb, b1, agg1f, W2allT, b2, T2f, out);
  k_fin     <<<NBD, 256, 0, stream>>>(T2f, perm, src, dst, et, seg_off, out);
}